// Round 5
// baseline (1042.082 us; speedup 1.0000x reference)
//
#include <hip/hip_runtime.h>
#include <cstdint>
#include <cstddef>

#define B_ 8
#define N_ 2048
#define H_ 8
#define D_ 32
#define U_ 256

typedef _Float16 half8 __attribute__((ext_vector_type(8)));
typedef _Float16 half4 __attribute__((ext_vector_type(4)));
typedef float float4v __attribute__((ext_vector_type(4)));

__device__ __forceinline__ float fast_exp2(float x) {
#if __has_builtin(__builtin_amdgcn_exp2f)
  return __builtin_amdgcn_exp2f(x);
#else
  return exp2f(x);
#endif
}

// ---------------------------------------------------------------------------
// K0: prep. blocks 0..511: X fp32->fp16. blocks 512..527: transpose W{q,k,v,o}
// -> WT[m][n][k] fp16 (4 blocks per matrix, 64-col slice each); q-scale
// log2(e)/sqrt(32) folded into WTq.
// ---------------------------------------------------------------------------
__global__ __launch_bounds__(256)
void k_prep(const float* __restrict__ X,
            const float* __restrict__ Wq, const float* __restrict__ Wk,
            const float* __restrict__ Wv, const float* __restrict__ Wo,
            _Float16* __restrict__ Xh, _Float16* __restrict__ WT)
{
  const int bid = blockIdx.x, tid = threadIdx.x;
  if (bid < 512) {
    const size_t base = ((size_t)bid * 256 + tid) * 32;
    const float* src = X + base;
    _Float16* dst = Xh + base;
#pragma unroll
    for (int i = 0; i < 4; ++i) {
      float4v a = *(const float4v*)(src + i * 8);
      float4v b = *(const float4v*)(src + i * 8 + 4);
      half8 h;
      h[0] = (_Float16)a[0]; h[1] = (_Float16)a[1];
      h[2] = (_Float16)a[2]; h[3] = (_Float16)a[3];
      h[4] = (_Float16)b[0]; h[5] = (_Float16)b[1];
      h[6] = (_Float16)b[2]; h[7] = (_Float16)b[3];
      *(half8*)(dst + i * 8) = h;
    }
  } else {
    const int id = bid - 512;          // 0..15
    const int m = id >> 2;             // 0=q 1=k 2=v 3=o
    const int n0 = (id & 3) * 64;      // 64-col slice
    const float* W = (m == 0) ? Wq : (m == 1) ? Wk : (m == 2) ? Wv : Wo;
    const float scale = (m == 0) ? 0.25505413f : 1.0f; // log2(e)/sqrt(32)
    _Float16* T = WT + (size_t)m * U_ * U_;
    __shared__ _Float16 Ts[64][72];
    const int r = tid >> 2, seg = tid & 3;
    for (int t = 0; t < 4; ++t) {
      const int k0 = t * 64;
      float4v a[4];
      const float* s = W + (size_t)(k0 + r) * U_ + n0 + seg * 16;
#pragma unroll
      for (int i = 0; i < 4; ++i) a[i] = *(const float4v*)(s + i * 4);
      __syncthreads();
#pragma unroll
      for (int i = 0; i < 4; ++i)
#pragma unroll
        for (int j = 0; j < 4; ++j)
          Ts[seg * 16 + i * 4 + j][r] = (_Float16)(a[i][j] * scale);
      __syncthreads();
      _Float16* d = T + (size_t)(n0 + r) * U_ + k0 + seg * 16;
      *(half8*)d       = *(const half8*)&Ts[r][seg * 16];
      *(half8*)(d + 8) = *(const half8*)&Ts[r][seg * 16 + 8];
    }
  }
}

// ---------------------------------------------------------------------------
// K1: QKV projection, LDS-free barrier-free register GEMM with VECTORIZED
// epilogues. grid (6,128): proj = bx>>1, 128-col half = bx&1; 128 rows/block.
// Q/K: operand-SWAPPED mfma (A = W^T rows -> M-dim = features) so each lane
// holds 4 consecutive features at fixed seq row -> direct half4 stores.
// V: original order (consecutive seq at fixed feature) -> half4 stores into
// VT[b][u][n].
// ---------------------------------------------------------------------------
__global__ __launch_bounds__(256, 4)
void k_qkv(const _Float16* __restrict__ Xh, const _Float16* __restrict__ WT,
           _Float16* __restrict__ Qg, _Float16* __restrict__ Kg,
           _Float16* __restrict__ VTg)
{
  const int tid  = threadIdx.x;
  const int lane = tid & 63;
  const int w    = tid >> 6;
  const int c    = lane & 15;
  const int qd   = lane >> 4;
  const int bx   = blockIdx.x;
  const int proj = bx >> 1;
  const int n0l  = (bx & 1) * 128;
  const int m0   = blockIdx.y * 128;

  const _Float16* Wp = WT + (size_t)proj * U_ * U_;
  const _Float16* arow0 = Xh + (size_t)(m0 + w * 32 + c) * U_ + qd * 8;
  const _Float16* arow1 = arow0 + (size_t)16 * U_;
  const _Float16* brow  = Wp + (size_t)(n0l + c) * U_ + qd * 8;

  const float4v zero4 = {0.f, 0.f, 0.f, 0.f};
  float4v acc[8][2];
#pragma unroll
  for (int i = 0; i < 8; ++i)
#pragma unroll
    for (int j = 0; j < 2; ++j) acc[i][j] = zero4;

#pragma unroll 2
  for (int ks = 0; ks < 8; ++ks) {
    const int k0 = ks * 32;
    half8 af0 = *(const half8*)(arow0 + k0);
    half8 af1 = *(const half8*)(arow1 + k0);
    half8 bf[8];
#pragma unroll
    for (int nt = 0; nt < 8; ++nt)
      bf[nt] = *(const half8*)(brow + (size_t)nt * 16 * U_ + k0);
    if (proj < 2) {
      // swapped: A = W (features as M-rows), B = X (seq as N-cols)
#pragma unroll
      for (int nt = 0; nt < 8; ++nt) {
        acc[nt][0] = __builtin_amdgcn_mfma_f32_16x16x32_f16(bf[nt], af0, acc[nt][0], 0, 0, 0);
        acc[nt][1] = __builtin_amdgcn_mfma_f32_16x16x32_f16(bf[nt], af1, acc[nt][1], 0, 0, 0);
      }
    } else {
      // original: A = X (seq as M-rows), B = W (features as N-cols)
#pragma unroll
      for (int nt = 0; nt < 8; ++nt) {
        acc[nt][0] = __builtin_amdgcn_mfma_f32_16x16x32_f16(af0, bf[nt], acc[nt][0], 0, 0, 0);
        acc[nt][1] = __builtin_amdgcn_mfma_f32_16x16x32_f16(af1, bf[nt], acc[nt][1], 0, 0, 0);
      }
    }
  }

  const int b   = m0 >> 11;
  const int nb0 = m0 & (N_ - 1);
  if (proj < 2) {
    // lane holds features n = n0l + nt*16 + qd*4 + r at seq = m0 + w*32 + mt*16 + c
    _Float16* Og = (proj == 0) ? Qg : Kg;
#pragma unroll
    for (int nt = 0; nt < 8; ++nt)
#pragma unroll
      for (int mt = 0; mt < 2; ++mt) {
        half4 hv;
#pragma unroll
        for (int r = 0; r < 4; ++r) hv[r] = (_Float16)acc[nt][mt][r];
        const int seq = nb0 + w * 32 + mt * 16 + c;
        *(half4*)(Og + (size_t)(b * N_ + seq) * U_ + n0l + nt * 16 + qd * 4) = hv;
      }
  } else {
    // lane holds seq = nb0 + w*32 + mt*16 + qd*4 + r at feature u = n0l + nt*16 + c
#pragma unroll
    for (int nt = 0; nt < 8; ++nt)
#pragma unroll
      for (int mt = 0; mt < 2; ++mt) {
        half4 hv;
#pragma unroll
        for (int r = 0; r < 4; ++r) hv[r] = (_Float16)acc[nt][mt][r];
        const int u = n0l + nt * 16 + c;
        const int seq = nb0 + w * 32 + mt * 16 + qd * 4;
        *(half4*)(VTg + (size_t)(b * U_ + u) * N_ + seq) = hv;
      }
  }
}

// ---------------------------------------------------------------------------
// K2: fused masked flash attention. Tq=32, Tk=32, grid 512, block 512 = 8
// waves = 8 heads. SINGLE-buffered LDS (35.5 KB) -> 4 blocks/CU, 32 waves/CU:
// latency hidden by TLP across blocks. Loads for kt+1 issued before compute
// of kt. Fixed-bias softmax p = exp2(s-8) (no online max; cancels in p/l).
// S^T = K*Q^T; P^T exits QK in the B-layout of mfma 16x16x16f16 -> PV in regs.
// V^T pad = 36 halves (18c mod 32 -> 16 distinct banks, conflict-free).
// ---------------------------------------------------------------------------
#define KS_H (32 * 264)
#define VT_H (256 * 36)

struct StageRegs {
  half8 k0, k1, v0, v1;
  int a0, a1;
};

__global__ __launch_bounds__(512, 8)
void k_attn(const _Float16* __restrict__ Qg, const _Float16* __restrict__ Kg,
            const _Float16* __restrict__ VTg, const int* __restrict__ Adj,
            _Float16* __restrict__ Cg)
{
  __shared__ __attribute__((aligned(16))) _Float16 Ks[KS_H];    // [32 key][264]
  __shared__ __attribute__((aligned(16))) _Float16 VTs[VT_H];   // [256 u][36]
  __shared__ __attribute__((aligned(8)))  unsigned int maskS[32];

  const int tid  = threadIdx.x;
  const int lane = tid & 63;
  const int w    = tid >> 6;   // head
  const int c    = lane & 15;
  const int qd   = lane >> 4;
  const int wg   = blockIdx.x;
  const int b    = wg & 7;     // XCD-L2 affinity: batch <-> XCD
  const int q0   = (wg >> 3) * 32;

  const _Float16* kptr = Kg + (size_t)(b * N_ + (tid >> 4)) * U_ + (tid & 15) * 16;
  const _Float16* vptr = VTg + (size_t)(b * U_ + (tid >> 1)) * N_ + (tid & 1) * 16;
  const int rr = lane >> 5;
  const int kk = lane & 31;
  const int* aptr = Adj + (size_t)(b * N_ + q0 + w * 4 + rr) * N_ + kk;

  half8 qb[2];
#pragma unroll
  for (int nt = 0; nt < 2; ++nt)
    qb[nt] = *(const half8*)(Qg + (size_t)(b * N_ + q0 + nt * 16 + c) * U_ + w * D_ + qd * 8);

  const float4v init4 = {-8.f, -8.f, -8.f, -8.f};
  const float4v zero4 = {0.f, 0.f, 0.f, 0.f};
  float4v acc[2][2];
#pragma unroll
  for (int i = 0; i < 2; ++i)
#pragma unroll
    for (int j = 0; j < 2; ++j) acc[i][j] = zero4;
  float lrow[2] = {0.f, 0.f};

  auto load_tile = [&](int kt) -> StageRegs {
    StageRegs r;
    const _Float16* ks = kptr + (size_t)kt * 32 * U_;
    const _Float16* vs = vptr + (size_t)kt * 32;
    const int* as = aptr + (size_t)kt * 32;
    r.k0 = *(const half8*)ks;  r.k1 = *(const half8*)(ks + 8);
    r.v0 = *(const half8*)vs;  r.v1 = *(const half8*)(vs + 8);
    r.a0 = as[0];
    r.a1 = as[2 * N_];
    return r;
  };
  auto store_tile = [&](const StageRegs& r) {
    _Float16* kd = &Ks[(tid >> 4) * 264 + (tid & 15) * 16];
    *(half8*)kd = r.k0;  *(half8*)(kd + 8) = r.k1;
    _Float16* vd = &VTs[(tid >> 1) * 36 + (tid & 1) * 16];
    *(half8*)vd = r.v0;  *(half8*)(vd + 8) = r.v1;
    unsigned long long bm;
    bm = __ballot(r.a0 > 0); if (lane == 0) *(unsigned long long*)&maskS[w * 4 + 0] = bm;
    bm = __ballot(r.a1 > 0); if (lane == 0) *(unsigned long long*)&maskS[w * 4 + 2] = bm;
  };
  auto compute_tile = [&]() {
    half8 ka0 = *(const half8*)&Ks[(0 * 16 + c) * 264 + w * D_ + qd * 8];
    half8 ka1 = *(const half8*)&Ks[(1 * 16 + c) * 264 + w * D_ + qd * 8];
    half4 va[2][2];
#pragma unroll
    for (int mt = 0; mt < 2; ++mt)
#pragma unroll
      for (int kc = 0; kc < 2; ++kc)
        va[mt][kc] = *(const half4*)&VTs[(w * D_ + mt * 16 + c) * 36 + kc * 16 + qd * 4];
#pragma unroll
    for (int nt = 0; nt < 2; ++nt) {
      float4v s0 = __builtin_amdgcn_mfma_f32_16x16x32_f16(ka0, qb[nt], init4, 0, 0, 0);
      float4v s1 = __builtin_amdgcn_mfma_f32_16x16x32_f16(ka1, qb[nt], init4, 0, 0, 0);
      const unsigned int mq = maskS[nt * 16 + c];
      const unsigned int t0 = mq >> (qd * 4);
      const unsigned int t1 = mq >> (16 + qd * 4);
      half4 pb0, pb1;
      float ls = 0.f;
#pragma unroll
      for (int r = 0; r < 4; ++r) {
        float e0 = fast_exp2(s0[r]);
        float e1 = fast_exp2(s1[r]);
        float p0 = ((t0 >> r) & 1u) ? e0 : 0.f;
        float p1 = ((t1 >> r) & 1u) ? e1 : 0.f;
        ls += p0 + p1;
        pb0[r] = (_Float16)p0;
        pb1[r] = (_Float16)p1;
      }
      lrow[nt] += ls;
      acc[0][nt] = __builtin_amdgcn_mfma_f32_16x16x16f16(va[0][0], pb0, acc[0][nt], 0, 0, 0);
      acc[0][nt] = __builtin_amdgcn_mfma_f32_16x16x16f16(va[0][1], pb1, acc[0][nt], 0, 0, 0);
      acc[1][nt] = __builtin_amdgcn_mfma_f32_16x16x16f16(va[1][0], pb0, acc[1][nt], 0, 0, 0);
      acc[1][nt] = __builtin_amdgcn_mfma_f32_16x16x16f16(va[1][1], pb1, acc[1][nt], 0, 0, 0);
    }
  };

  {
    StageRegs r = load_tile(0);
    store_tile(r);
  }
  __syncthreads();

#pragma unroll 1
  for (int kt = 0; kt < 64; ++kt) {
    if (kt + 1 < 64) {
      StageRegs r = load_tile(kt + 1);   // issue loads early; land during compute
      compute_tile();
      __syncthreads();                   // all reads of tile kt done
      store_tile(r);
      __syncthreads();                   // tile kt+1 visible
    } else {
      compute_tile();
    }
  }

  // epilogue: reduce l across qd-groups, normalize, store via LDS
  float rinv[2];
#pragma unroll
  for (int nt = 0; nt < 2; ++nt) {
    float l = lrow[nt];
    l += __shfl_xor(l, 16, 64);
    l += __shfl_xor(l, 32, 64);
    rinv[nt] = (l > 0.f) ? 1.f / l : 0.f;
  }
  __syncthreads();
  _Float16* ctxS = Ks; // [32 q][264]
#pragma unroll
  for (int mt = 0; mt < 2; ++mt)
#pragma unroll
    for (int nt = 0; nt < 2; ++nt) {
      half4 hv;
#pragma unroll
      for (int r = 0; r < 4; ++r)
        hv[r] = (_Float16)(acc[mt][nt][r] * rinv[nt]);
      *(half4*)&ctxS[(nt * 16 + c) * 264 + w * D_ + mt * 16 + qd * 4] = hv;
    }
  __syncthreads();
  {
    const int row = tid >> 4;      // 0..31
    const int seg = tid & 15;      // 16 halves each
    _Float16* dst = Cg + (size_t)(b * N_ + q0 + row) * U_ + seg * 16;
    *(half8*)dst       = *(const half8*)&ctxS[row * 264 + seg * 16];
    *(half8*)(dst + 8) = *(const half8*)&ctxS[row * 264 + seg * 16 + 8];
  }
}

// ---------------------------------------------------------------------------
// K3: output projection, LDS-free register GEMM, operand-swapped so each lane
// holds 4 consecutive output features -> direct float4 stores (+float4 bias).
// grid (2,128).
// ---------------------------------------------------------------------------
__global__ __launch_bounds__(256, 4)
void k_out(const _Float16* __restrict__ Cg, const _Float16* __restrict__ WTo,
           const float* __restrict__ bo, float* __restrict__ Out)
{
  const int tid  = threadIdx.x;
  const int lane = tid & 63;
  const int w    = tid >> 6;
  const int c    = lane & 15;
  const int qd   = lane >> 4;
  const int n0l  = blockIdx.x * 128;
  const int m0   = blockIdx.y * 128;

  const _Float16* arow0 = Cg + (size_t)(m0 + w * 32 + c) * U_ + qd * 8;
  const _Float16* arow1 = arow0 + (size_t)16 * U_;
  const _Float16* brow  = WTo + (size_t)(n0l + c) * U_ + qd * 8;

  const float4v zero4 = {0.f, 0.f, 0.f, 0.f};
  float4v acc[8][2];
#pragma unroll
  for (int i = 0; i < 8; ++i)
#pragma unroll
    for (int j = 0; j < 2; ++j) acc[i][j] = zero4;

#pragma unroll 2
  for (int ks = 0; ks < 8; ++ks) {
    const int k0 = ks * 32;
    half8 af0 = *(const half8*)(arow0 + k0);
    half8 af1 = *(const half8*)(arow1 + k0);
    half8 bf[8];
#pragma unroll
    for (int nt = 0; nt < 8; ++nt)
      bf[nt] = *(const half8*)(brow + (size_t)nt * 16 * U_ + k0);
#pragma unroll
    for (int nt = 0; nt < 8; ++nt) {
      acc[nt][0] = __builtin_amdgcn_mfma_f32_16x16x32_f16(bf[nt], af0, acc[nt][0], 0, 0, 0);
      acc[nt][1] = __builtin_amdgcn_mfma_f32_16x16x32_f16(bf[nt], af1, acc[nt][1], 0, 0, 0);
    }
  }

  // lane holds features n = n0l + nt*16 + qd*4 + {0..3} at seq = m0+w*32+mt*16+c
#pragma unroll
  for (int nt = 0; nt < 8; ++nt) {
    const float4v bias = *(const float4v*)(bo + n0l + nt * 16 + qd * 4);
#pragma unroll
    for (int mt = 0; mt < 2; ++mt) {
      const int seq = m0 + w * 32 + mt * 16 + c;
      float4v v = acc[nt][mt] + bias;
      *(float4v*)(Out + (size_t)seq * U_ + n0l + nt * 16 + qd * 4) = v;
    }
  }
}

// ---------------------------------------------------------------------------
extern "C" void kernel_launch(void* const* d_in, const int* in_sizes, int n_in,
                              void* d_out, int out_size, void* d_ws, size_t ws_size,
                              hipStream_t stream) {
  const float* X   = (const float*)d_in[0];
  const int*   Adj = (const int*)d_in[1];
  const float* Wq  = (const float*)d_in[2];
  const float* Wk  = (const float*)d_in[3];
  const float* Wv  = (const float*)d_in[4];
  const float* Wo  = (const float*)d_in[5];
  const float* bo  = (const float*)d_in[6];
  float* Out = (float*)d_out;

  const size_t elems = (size_t)B_ * N_ * U_; // 4.19M halves = 8.39 MB each
  _Float16* Qg  = (_Float16*)d_ws;
  _Float16* Kg  = Qg + elems;
  _Float16* VTg = Kg + elems;
  _Float16* Xh  = VTg + elems;       // aliased: Cg reuses Xh after k_qkv
  _Float16* Cg  = Xh;
  _Float16* WT  = Xh + elems;        // 4 * 256*256 halves = 512 KB

  k_prep<<<dim3(528), 256, 0, stream>>>(X, Wq, Wk, Wv, Wo, Xh, WT);
  k_qkv<<<dim3(6, 128), 256, 0, stream>>>(Xh, WT, Qg, Kg, VTg);
  k_attn<<<dim3(512), 512, 0, stream>>>(Qg, Kg, VTg, Adj, Cg);
  k_out<<<dim3(2, 128), 256, 0, stream>>>(Cg, WT + 3 * U_ * U_, bo, Out);
}

// Round 6
// 485.149 us; speedup vs baseline: 2.1480x; 2.1480x over previous
//
#include <hip/hip_runtime.h>
#include <cstdint>
#include <cstddef>

#define B_ 8
#define N_ 2048
#define H_ 8
#define D_ 32
#define U_ 256

typedef _Float16 half8 __attribute__((ext_vector_type(8)));
typedef _Float16 half4 __attribute__((ext_vector_type(4)));
typedef float float4v __attribute__((ext_vector_type(4)));

__device__ __forceinline__ float fast_exp2(float x) {
#if __has_builtin(__builtin_amdgcn_exp2f)
  return __builtin_amdgcn_exp2f(x);
#else
  return exp2f(x);
#endif
}

// ---------------------------------------------------------------------------
// K0: prep.
// blocks 0..15: transpose W{q,k,v,o} -> WT[m][n][k] fp16 (4 blocks per matrix,
//   64-col slice each); q-scale log2(e)/sqrt(32) folded into WTq.
// blocks 16..2063: bitpack adjacency -> mask32[b][kt][q] (bit j = Adj[b][q][kt*32+j]>0).
//   Wave handles one (b, q-pair), streams kt 0..63 (2 rows x 128B contiguous reads).
// ---------------------------------------------------------------------------
__global__ __launch_bounds__(256)
void k_prep(const float* __restrict__ Wq, const float* __restrict__ Wk,
            const float* __restrict__ Wv, const float* __restrict__ Wo,
            const int* __restrict__ Adj,
            _Float16* __restrict__ WT, unsigned int* __restrict__ mask32)
{
  const int bid = blockIdx.x, tid = threadIdx.x;
  if (bid < 16) {
    const int m = bid >> 2;            // 0=q 1=k 2=v 3=o
    const int n0 = (bid & 3) * 64;     // 64-col slice
    const float* W = (m == 0) ? Wq : (m == 1) ? Wk : (m == 2) ? Wv : Wo;
    const float scale = (m == 0) ? 0.25505413f : 1.0f; // log2(e)/sqrt(32)
    _Float16* T = WT + (size_t)m * U_ * U_;
    __shared__ _Float16 Ts[64][72];
    const int r = tid >> 2, seg = tid & 3;
    for (int t = 0; t < 4; ++t) {
      const int k0 = t * 64;
      float4v a[4];
      const float* s = W + (size_t)(k0 + r) * U_ + n0 + seg * 16;
#pragma unroll
      for (int i = 0; i < 4; ++i) a[i] = *(const float4v*)(s + i * 4);
      __syncthreads();
#pragma unroll
      for (int i = 0; i < 4; ++i)
#pragma unroll
        for (int j = 0; j < 4; ++j)
          Ts[seg * 16 + i * 4 + j][r] = (_Float16)(a[i][j] * scale);
      __syncthreads();
      _Float16* d = T + (size_t)(n0 + r) * U_ + k0 + seg * 16;
      *(half8*)d       = *(const half8*)&Ts[r][seg * 16];
      *(half8*)(d + 8) = *(const half8*)&Ts[r][seg * 16 + 8];
    }
  } else {
    const int lane = tid & 63;
    const int w = tid >> 6;
    const int gw = (bid - 16) * 4 + w;   // 0..8191
    const int b = gw >> 10;              // batch
    const int q = (gw & 1023) * 2;       // even q row
    const int rr = lane >> 5;
    const int kk = lane & 31;
    const int* src = Adj + (size_t)(b * N_ + q + rr) * N_ + kk;
    unsigned int* mrow = mask32 + (size_t)b * 64 * N_ + q;
#pragma unroll 4
    for (int kt = 0; kt < 64; ++kt) {
      const int a = src[kt * 32];
      const unsigned long long bm = __ballot(a > 0);
      if (lane == 0)
        *(unsigned long long*)(mrow + (size_t)kt * N_) = bm;
    }
  }
}

// ---------------------------------------------------------------------------
// K1: QKV projection, LDS-free register GEMM reading X fp32 directly (cvt in
// regs). grid (6,128): proj = bx>>1, 128-col half = bx&1; 128 rows/block.
// Q/K: operand-swapped mfma -> lane holds 4 consecutive features -> half4
// stores. V: normal order -> half4 seq-stores into VT[b][u][n].
// ---------------------------------------------------------------------------
__global__ __launch_bounds__(256, 3)
void k_qkv(const float* __restrict__ X, const _Float16* __restrict__ WT,
           _Float16* __restrict__ Qg, _Float16* __restrict__ Kg,
           _Float16* __restrict__ VTg)
{
  const int tid  = threadIdx.x;
  const int lane = tid & 63;
  const int w    = tid >> 6;
  const int c    = lane & 15;
  const int qd   = lane >> 4;
  const int bx   = blockIdx.x;
  const int proj = bx >> 1;
  const int n0l  = (bx & 1) * 128;
  const int m0   = blockIdx.y * 128;

  const _Float16* Wp = WT + (size_t)proj * U_ * U_;
  const float* arow0 = X + (size_t)(m0 + w * 32 + c) * U_ + qd * 8;
  const float* arow1 = arow0 + (size_t)16 * U_;
  const _Float16* brow = Wp + (size_t)(n0l + c) * U_ + qd * 8;

  const float4v zero4 = {0.f, 0.f, 0.f, 0.f};
  float4v acc[8][2];
#pragma unroll
  for (int i = 0; i < 8; ++i)
#pragma unroll
    for (int j = 0; j < 2; ++j) acc[i][j] = zero4;

#pragma unroll 2
  for (int ks = 0; ks < 8; ++ks) {
    const int k0 = ks * 32;
    float4v x00 = *(const float4v*)(arow0 + k0);
    float4v x01 = *(const float4v*)(arow0 + k0 + 4);
    float4v x10 = *(const float4v*)(arow1 + k0);
    float4v x11 = *(const float4v*)(arow1 + k0 + 4);
    half8 af0, af1;
#pragma unroll
    for (int j = 0; j < 4; ++j) {
      af0[j] = (_Float16)x00[j]; af0[j + 4] = (_Float16)x01[j];
      af1[j] = (_Float16)x10[j]; af1[j + 4] = (_Float16)x11[j];
    }
    half8 bf[8];
#pragma unroll
    for (int nt = 0; nt < 8; ++nt)
      bf[nt] = *(const half8*)(brow + (size_t)nt * 16 * U_ + k0);
    if (proj < 2) {
#pragma unroll
      for (int nt = 0; nt < 8; ++nt) {
        acc[nt][0] = __builtin_amdgcn_mfma_f32_16x16x32_f16(bf[nt], af0, acc[nt][0], 0, 0, 0);
        acc[nt][1] = __builtin_amdgcn_mfma_f32_16x16x32_f16(bf[nt], af1, acc[nt][1], 0, 0, 0);
      }
    } else {
#pragma unroll
      for (int nt = 0; nt < 8; ++nt) {
        acc[nt][0] = __builtin_amdgcn_mfma_f32_16x16x32_f16(af0, bf[nt], acc[nt][0], 0, 0, 0);
        acc[nt][1] = __builtin_amdgcn_mfma_f32_16x16x32_f16(af1, bf[nt], acc[nt][1], 0, 0, 0);
      }
    }
  }

  const int b   = m0 >> 11;
  const int nb0 = m0 & (N_ - 1);
  if (proj < 2) {
    _Float16* Og = (proj == 0) ? Qg : Kg;
#pragma unroll
    for (int nt = 0; nt < 8; ++nt)
#pragma unroll
      for (int mt = 0; mt < 2; ++mt) {
        half4 hv;
#pragma unroll
        for (int r = 0; r < 4; ++r) hv[r] = (_Float16)acc[nt][mt][r];
        const int seq = nb0 + w * 32 + mt * 16 + c;
        *(half4*)(Og + (size_t)(b * N_ + seq) * U_ + n0l + nt * 16 + qd * 4) = hv;
      }
  } else {
#pragma unroll
    for (int nt = 0; nt < 8; ++nt)
#pragma unroll
      for (int mt = 0; mt < 2; ++mt) {
        half4 hv;
#pragma unroll
        for (int r = 0; r < 4; ++r) hv[r] = (_Float16)acc[nt][mt][r];
        const int u = n0l + nt * 16 + c;
        const int seq = nb0 + w * 32 + mt * 16 + qd * 4;
        *(half4*)(VTg + (size_t)(b * U_ + u) * N_ + seq) = hv;
      }
  }
}

// ---------------------------------------------------------------------------
// K2: fused masked flash attention — BARRIER-FREE, K/V-LDS-FREE.
// wave = (head h, 32-q tile); block = 256 thr = 4 waves; grid 1024 -> 4096
// waves = exactly 16 waves/CU, all work resident. b = blockIdx&7 -> batch
// pinned to one XCD; per-batch K(1MB)+VT(1MB)+mask(0.5MB)+Q stream fit its L2.
// K frags (A-layout, 16B/lane) and V^T frags (8B/lane) loaded straight from
// global; adjacency comes bitpacked from mask32 (2 dwords/lane/iter).
// Fixed-bias softmax p = exp2(s-8) (cancels in p/l). One-tile register
// prefetch; the only __syncthreads is the epilogue LDS transpose.
// ---------------------------------------------------------------------------
struct Frag {
  half8 ka[2];
  half4 va[2][2];
  unsigned int mq[2];
};

__global__ __launch_bounds__(256, 4)
void k_attn(const _Float16* __restrict__ Qg, const _Float16* __restrict__ Kg,
            const _Float16* __restrict__ VTg, const unsigned int* __restrict__ mask32,
            _Float16* __restrict__ Cg)
{
  __shared__ __attribute__((aligned(16))) _Float16 ctxS[4][32 * 36];

  const int tid  = threadIdx.x;
  const int lane = tid & 63;
  const int w    = tid >> 6;
  const int c    = lane & 15;
  const int qd   = lane >> 4;
  const int b    = blockIdx.x & 7;                 // batch <-> XCD
  const int idx  = (blockIdx.x >> 3) * 4 + w;      // 0..511
  const int h    = idx & 7;
  const int q0   = (idx >> 3) * 32;

  const _Float16* kbase = Kg + (size_t)b * N_ * U_ + h * D_ + qd * 8;
  const _Float16* vbase = VTg + ((size_t)b * U_ + h * D_) * N_;
  const unsigned int* mbase = mask32 + (size_t)b * 64 * N_ + q0;

  half8 qb[2];
#pragma unroll
  for (int nt = 0; nt < 2; ++nt)
    qb[nt] = *(const half8*)(Qg + (size_t)(b * N_ + q0 + nt * 16 + c) * U_ + h * D_ + qd * 8);

  const float4v init4 = {-8.f, -8.f, -8.f, -8.f};
  const float4v zero4 = {0.f, 0.f, 0.f, 0.f};
  float4v acc[2][2];
#pragma unroll
  for (int i = 0; i < 2; ++i)
#pragma unroll
    for (int j = 0; j < 2; ++j) acc[i][j] = zero4;
  float lrow[2] = {0.f, 0.f};

  auto load_frags = [&](int kt) -> Frag {
    Frag f;
#pragma unroll
    for (int mt = 0; mt < 2; ++mt)
      f.ka[mt] = *(const half8*)(kbase + (size_t)(kt * 32 + mt * 16 + c) * U_);
#pragma unroll
    for (int mt = 0; mt < 2; ++mt)
#pragma unroll
      for (int kc = 0; kc < 2; ++kc)
        f.va[mt][kc] = *(const half4*)(vbase + (size_t)(mt * 16 + c) * N_ + kt * 32 + kc * 16 + qd * 4);
#pragma unroll
    for (int nt = 0; nt < 2; ++nt)
      f.mq[nt] = mbase[(size_t)kt * N_ + nt * 16 + c];
    return f;
  };
  auto compute = [&](const Frag& f) {
#pragma unroll
    for (int nt = 0; nt < 2; ++nt) {
      float4v s0 = __builtin_amdgcn_mfma_f32_16x16x32_f16(f.ka[0], qb[nt], init4, 0, 0, 0);
      float4v s1 = __builtin_amdgcn_mfma_f32_16x16x32_f16(f.ka[1], qb[nt], init4, 0, 0, 0);
      const unsigned int t0 = f.mq[nt] >> (qd * 4);
      const unsigned int t1 = f.mq[nt] >> (16 + qd * 4);
      half4 pb0, pb1;
      float ls = 0.f;
#pragma unroll
      for (int r = 0; r < 4; ++r) {
        float e0 = fast_exp2(s0[r]);
        float e1 = fast_exp2(s1[r]);
        float p0 = ((t0 >> r) & 1u) ? e0 : 0.f;
        float p1 = ((t1 >> r) & 1u) ? e1 : 0.f;
        ls += p0 + p1;
        pb0[r] = (_Float16)p0;
        pb1[r] = (_Float16)p1;
      }
      lrow[nt] += ls;
      acc[0][nt] = __builtin_amdgcn_mfma_f32_16x16x16f16(f.va[0][0], pb0, acc[0][nt], 0, 0, 0);
      acc[0][nt] = __builtin_amdgcn_mfma_f32_16x16x16f16(f.va[0][1], pb1, acc[0][nt], 0, 0, 0);
      acc[1][nt] = __builtin_amdgcn_mfma_f32_16x16x16f16(f.va[1][0], pb0, acc[1][nt], 0, 0, 0);
      acc[1][nt] = __builtin_amdgcn_mfma_f32_16x16x16f16(f.va[1][1], pb1, acc[1][nt], 0, 0, 0);
    }
  };

  Frag cur = load_frags(0);
#pragma unroll 1
  for (int kt = 0; kt < 63; ++kt) {
    Frag nxt = load_frags(kt + 1);   // in flight during compute(cur)
    compute(cur);
    cur = nxt;
  }
  compute(cur);

  // epilogue: reduce l across qd-groups, normalize, transpose via per-wave LDS
  float rinv[2];
#pragma unroll
  for (int nt = 0; nt < 2; ++nt) {
    float l = lrow[nt];
    l += __shfl_xor(l, 16, 64);
    l += __shfl_xor(l, 32, 64);
    rinv[nt] = (l > 0.f) ? 1.f / l : 0.f;
  }
#pragma unroll
  for (int mt = 0; mt < 2; ++mt)
#pragma unroll
    for (int nt = 0; nt < 2; ++nt) {
      half4 hv;
#pragma unroll
      for (int r = 0; r < 4; ++r)
        hv[r] = (_Float16)(acc[mt][nt][r] * rinv[nt]);
      *(half4*)&ctxS[w][(nt * 16 + c) * 36 + mt * 16 + qd * 4] = hv;
    }
  __syncthreads();
  {
    const int row = lane >> 1;   // 0..31 (q within tile)
    const int seg = lane & 1;    // 16-half segment of the 32-d slice
    _Float16* dst = Cg + (size_t)(b * N_ + q0 + row) * U_ + h * D_ + seg * 16;
    *(half8*)dst       = *(const half8*)&ctxS[w][row * 36 + seg * 16];
    *(half8*)(dst + 8) = *(const half8*)&ctxS[w][row * 36 + seg * 16 + 8];
  }
}

// ---------------------------------------------------------------------------
// K3: output projection, LDS-free register GEMM, operand-swapped -> float4
// stores with float4 bias. grid (2,128).
// ---------------------------------------------------------------------------
__global__ __launch_bounds__(256, 3)
void k_out(const _Float16* __restrict__ Cg, const _Float16* __restrict__ WTo,
           const float* __restrict__ bo, float* __restrict__ Out)
{
  const int tid  = threadIdx.x;
  const int lane = tid & 63;
  const int w    = tid >> 6;
  const int c    = lane & 15;
  const int qd   = lane >> 4;
  const int n0l  = blockIdx.x * 128;
  const int m0   = blockIdx.y * 128;

  const _Float16* arow0 = Cg + (size_t)(m0 + w * 32 + c) * U_ + qd * 8;
  const _Float16* arow1 = arow0 + (size_t)16 * U_;
  const _Float16* brow  = WTo + (size_t)(n0l + c) * U_ + qd * 8;

  const float4v zero4 = {0.f, 0.f, 0.f, 0.f};
  float4v acc[8][2];
#pragma unroll
  for (int i = 0; i < 8; ++i)
#pragma unroll
    for (int j = 0; j < 2; ++j) acc[i][j] = zero4;

#pragma unroll 2
  for (int ks = 0; ks < 8; ++ks) {
    const int k0 = ks * 32;
    half8 af0 = *(const half8*)(arow0 + k0);
    half8 af1 = *(const half8*)(arow1 + k0);
    half8 bf[8];
#pragma unroll
    for (int nt = 0; nt < 8; ++nt)
      bf[nt] = *(const half8*)(brow + (size_t)nt * 16 * U_ + k0);
#pragma unroll
    for (int nt = 0; nt < 8; ++nt) {
      acc[nt][0] = __builtin_amdgcn_mfma_f32_16x16x32_f16(bf[nt], af0, acc[nt][0], 0, 0, 0);
      acc[nt][1] = __builtin_amdgcn_mfma_f32_16x16x32_f16(bf[nt], af1, acc[nt][1], 0, 0, 0);
    }
  }

#pragma unroll
  for (int nt = 0; nt < 8; ++nt) {
    const float4v bias = *(const float4v*)(bo + n0l + nt * 16 + qd * 4);
#pragma unroll
    for (int mt = 0; mt < 2; ++mt) {
      const int seq = m0 + w * 32 + mt * 16 + c;
      float4v v = acc[nt][mt] + bias;
      *(float4v*)(Out + (size_t)seq * U_ + n0l + nt * 16 + qd * 4) = v;
    }
  }
}

// ---------------------------------------------------------------------------
extern "C" void kernel_launch(void* const* d_in, const int* in_sizes, int n_in,
                              void* d_out, int out_size, void* d_ws, size_t ws_size,
                              hipStream_t stream) {
  const float* X   = (const float*)d_in[0];
  const int*   Adj = (const int*)d_in[1];
  const float* Wq  = (const float*)d_in[2];
  const float* Wk  = (const float*)d_in[3];
  const float* Wv  = (const float*)d_in[4];
  const float* Wo  = (const float*)d_in[5];
  const float* bo  = (const float*)d_in[6];
  float* Out = (float*)d_out;

  const size_t elems = (size_t)B_ * N_ * U_;  // 4.19M halves = 8.39 MB each
  _Float16* Qg  = (_Float16*)d_ws;
  _Float16* Kg  = Qg + elems;
  _Float16* VTg = Kg + elems;
  _Float16* Cg  = VTg + elems;
  _Float16* WT  = Cg + elems;                       // 4*256*256 halves = 512 KB
  unsigned int* mask32 = (unsigned int*)(WT + 4 * U_ * U_); // 8*64*2048 u32 = 4 MB

  k_prep<<<dim3(2064), 256, 0, stream>>>(Wq, Wk, Wv, Wo, Adj, WT, mask32);
  k_qkv<<<dim3(6, 128), 256, 0, stream>>>(X, WT, Qg, Kg, VTg);
  k_attn<<<dim3(1024), 256, 0, stream>>>(Qg, Kg, VTg, mask32, Cg);
  k_out<<<dim3(2, 128), 256, 0, stream>>>(Cg, WT + 3 * U_ * U_, bo, Out);
}

// Round 7
// 427.259 us; speedup vs baseline: 2.4390x; 1.1355x over previous
//
#include <hip/hip_runtime.h>
#include <cstdint>
#include <cstddef>

#define B_ 8
#define N_ 2048
#define H_ 8
#define D_ 32
#define U_ 256

typedef _Float16 half8 __attribute__((ext_vector_type(8)));
typedef _Float16 half4 __attribute__((ext_vector_type(4)));
typedef float float4v __attribute__((ext_vector_type(4)));

__device__ __forceinline__ float fast_exp2(float x) {
#if __has_builtin(__builtin_amdgcn_exp2f)
  return __builtin_amdgcn_exp2f(x);
#else
  return exp2f(x);
#endif
}

// ---------------------------------------------------------------------------
// K0: prep (2576 blocks).
//  bid 0..15   : transpose W{q,k,v,o} -> WT[m][n][k] fp16; q-scale folded.
//  bid 16..527 : X fp32 -> fp16 (Xh).
//  bid 528..   : bitpack adjacency -> mask32[b][kt][q] (bit j = Adj[b][q][kt*32+j]>0).
// ---------------------------------------------------------------------------
__global__ __launch_bounds__(256)
void k_prep(const float* __restrict__ X,
            const float* __restrict__ Wq, const float* __restrict__ Wk,
            const float* __restrict__ Wv, const float* __restrict__ Wo,
            const int* __restrict__ Adj,
            _Float16* __restrict__ Xh, _Float16* __restrict__ WT,
            unsigned int* __restrict__ mask32)
{
  const int bid = blockIdx.x, tid = threadIdx.x;
  if (bid < 16) {
    const int m = bid >> 2;            // 0=q 1=k 2=v 3=o
    const int n0 = (bid & 3) * 64;     // 64-col slice
    const float* W = (m == 0) ? Wq : (m == 1) ? Wk : (m == 2) ? Wv : Wo;
    const float scale = (m == 0) ? 0.25505413f : 1.0f; // log2(e)/sqrt(32)
    _Float16* T = WT + (size_t)m * U_ * U_;
    __shared__ _Float16 Ts[64][72];
    const int r = tid >> 2, seg = tid & 3;
    for (int t = 0; t < 4; ++t) {
      const int k0 = t * 64;
      float4v a[4];
      const float* s = W + (size_t)(k0 + r) * U_ + n0 + seg * 16;
#pragma unroll
      for (int i = 0; i < 4; ++i) a[i] = *(const float4v*)(s + i * 4);
      __syncthreads();
#pragma unroll
      for (int i = 0; i < 4; ++i)
#pragma unroll
        for (int j = 0; j < 4; ++j)
          Ts[seg * 16 + i * 4 + j][r] = (_Float16)(a[i][j] * scale);
      __syncthreads();
      _Float16* d = T + (size_t)(n0 + r) * U_ + k0 + seg * 16;
      *(half8*)d       = *(const half8*)&Ts[r][seg * 16];
      *(half8*)(d + 8) = *(const half8*)&Ts[r][seg * 16 + 8];
    }
  } else if (bid < 528) {
    const size_t base = ((size_t)(bid - 16) * 256 + tid) * 32;
    const float* src = X + base;
    _Float16* dst = Xh + base;
#pragma unroll
    for (int i = 0; i < 4; ++i) {
      float4v a = *(const float4v*)(src + i * 8);
      float4v b = *(const float4v*)(src + i * 8 + 4);
      half8 h;
      h[0] = (_Float16)a[0]; h[1] = (_Float16)a[1];
      h[2] = (_Float16)a[2]; h[3] = (_Float16)a[3];
      h[4] = (_Float16)b[0]; h[5] = (_Float16)b[1];
      h[6] = (_Float16)b[2]; h[7] = (_Float16)b[3];
      *(half8*)(dst + i * 8) = h;
    }
  } else {
    const int lane = tid & 63;
    const int w = tid >> 6;
    const int gw = (bid - 528) * 4 + w;  // 0..8191
    const int b = gw >> 10;              // batch
    const int q = (gw & 1023) * 2;       // even q row
    const int rr = lane >> 5;
    const int kk = lane & 31;
    const int* src = Adj + (size_t)(b * N_ + q + rr) * N_ + kk;
    unsigned int* mrow = mask32 + (size_t)b * 64 * N_ + q;
#pragma unroll 4
    for (int kt = 0; kt < 64; ++kt) {
      const int a = src[kt * 32];
      const unsigned long long bm = __ballot(a > 0);
      if (lane == 0)
        *(unsigned long long*)(mrow + (size_t)kt * N_) = bm;
    }
  }
}

// ---------------------------------------------------------------------------
// K1: QKV projection, LDS-free register GEMM on fp16 Xh. grid (6,256):
// proj = bx>>1, 128-col half = bx&1; 64 rows/block (wave = 16 rows), K=256.
// Q/K: operand-swapped mfma -> lane holds 4 consecutive features -> half4
// stores. V: normal order -> half4 seq-stores into VT[b][u][n].
// ---------------------------------------------------------------------------
__global__ __launch_bounds__(256, 4)
void k_qkv(const _Float16* __restrict__ Xh, const _Float16* __restrict__ WT,
           _Float16* __restrict__ Qg, _Float16* __restrict__ Kg,
           _Float16* __restrict__ VTg)
{
  const int tid  = threadIdx.x;
  const int lane = tid & 63;
  const int w    = tid >> 6;
  const int c    = lane & 15;
  const int qd   = lane >> 4;
  const int bx   = blockIdx.x;
  const int proj = bx >> 1;
  const int n0l  = (bx & 1) * 128;
  const int m0   = blockIdx.y * 64;

  const _Float16* Wp = WT + (size_t)proj * U_ * U_;
  const _Float16* arow = Xh + (size_t)(m0 + w * 16 + c) * U_ + qd * 8;
  const _Float16* brow = Wp + (size_t)(n0l + c) * U_ + qd * 8;

  const float4v zero4 = {0.f, 0.f, 0.f, 0.f};
  float4v acc[8];
#pragma unroll
  for (int i = 0; i < 8; ++i) acc[i] = zero4;

#pragma unroll 2
  for (int ks = 0; ks < 8; ++ks) {
    const int k0 = ks * 32;
    half8 af = *(const half8*)(arow + k0);
    half8 bf[8];
#pragma unroll
    for (int nt = 0; nt < 8; ++nt)
      bf[nt] = *(const half8*)(brow + (size_t)nt * 16 * U_ + k0);
    if (proj < 2) {
#pragma unroll
      for (int nt = 0; nt < 8; ++nt)
        acc[nt] = __builtin_amdgcn_mfma_f32_16x16x32_f16(bf[nt], af, acc[nt], 0, 0, 0);
    } else {
#pragma unroll
      for (int nt = 0; nt < 8; ++nt)
        acc[nt] = __builtin_amdgcn_mfma_f32_16x16x32_f16(af, bf[nt], acc[nt], 0, 0, 0);
    }
  }

  const int b   = m0 >> 11;
  const int nb0 = m0 & (N_ - 1);
  if (proj < 2) {
    // lane holds features n0l+nt*16+qd*4+{0..3} at seq nb0+w*16+c
    _Float16* Og = (proj == 0) ? Qg : Kg;
#pragma unroll
    for (int nt = 0; nt < 8; ++nt) {
      half4 hv;
#pragma unroll
      for (int r = 0; r < 4; ++r) hv[r] = (_Float16)acc[nt][r];
      const int seq = nb0 + w * 16 + c;
      *(half4*)(Og + (size_t)(b * N_ + seq) * U_ + n0l + nt * 16 + qd * 4) = hv;
    }
  } else {
    // lane holds seq nb0+w*16+qd*4+{0..3} at feature n0l+nt*16+c
#pragma unroll
    for (int nt = 0; nt < 8; ++nt) {
      half4 hv;
#pragma unroll
      for (int r = 0; r < 4; ++r) hv[r] = (_Float16)acc[nt][r];
      const int u = n0l + nt * 16 + c;
      const int seq = nb0 + w * 16 + qd * 4;
      *(half4*)(VTg + (size_t)(b * U_ + u) * N_ + seq) = hv;
    }
  }
}

// ---------------------------------------------------------------------------
// K2: fused masked flash attention. Tq=32, Tk=32, grid 512, block 512 = 8
// waves = 8 heads. SINGLE-buffered LDS (34.6 KB) -> 3-4 blocks/CU. Register
// load of tile kt+1 issued before compute(kt), anchored by the barrier pair
// (compiler cannot sink loads past the LDS stores that feed other waves).
// Masks precomputed (mask32). Fixed-bias softmax p = exp2(s-8), cancels in
// p/l. S^T = K*Q^T; P^T exits QK in B-layout of mfma 16x16x16f16 -> PV in
// registers. V^T pad 36 halves -> 16 distinct banks. K pad 264.
// ---------------------------------------------------------------------------
#define KS_B 16896   // 32*264*2
#define VT_B 18432   // 256*36*2

struct StageRegs {
  half8 k0, k1, v0, v1;
  unsigned int m;
};

__global__ __launch_bounds__(512, 4)
void k_attn(const _Float16* __restrict__ Qg, const _Float16* __restrict__ Kg,
            const _Float16* __restrict__ VTg, const unsigned int* __restrict__ mask32,
            _Float16* __restrict__ Cg)
{
  __shared__ __attribute__((aligned(16))) char smem[KS_B + VT_B + 128];
  _Float16* Ks  = (_Float16*)smem;              // [32 key][264]
  _Float16* VTs = (_Float16*)(smem + KS_B);     // [256 u][36]
  unsigned int* maskS = (unsigned int*)(smem + KS_B + VT_B); // [32 q]

  const int tid  = threadIdx.x;
  const int lane = tid & 63;
  const int w    = tid >> 6;   // head
  const int c    = lane & 15;
  const int qd   = lane >> 4;
  const int wg   = blockIdx.x;
  const int b    = wg & 7;     // batch <-> XCD affinity
  const int q0   = (wg >> 3) * 32;

  const _Float16* kptr = Kg + (size_t)(b * N_ + (tid >> 4)) * U_ + (tid & 15) * 16;
  const _Float16* vptr = VTg + (size_t)(b * U_ + (tid >> 1)) * N_ + (tid & 1) * 16;
  const unsigned int* mptr = mask32 + (size_t)b * 64 * N_ + q0 + (tid & 31);

  half8 qb[2];
#pragma unroll
  for (int nt = 0; nt < 2; ++nt)
    qb[nt] = *(const half8*)(Qg + (size_t)(b * N_ + q0 + nt * 16 + c) * U_ + w * D_ + qd * 8);

  const float4v init4 = {-8.f, -8.f, -8.f, -8.f}; // exp2 bias, cancels in p/l
  const float4v zero4 = {0.f, 0.f, 0.f, 0.f};
  float4v acc[2][2];
#pragma unroll
  for (int i = 0; i < 2; ++i)
#pragma unroll
    for (int j = 0; j < 2; ++j) acc[i][j] = zero4;
  float lrow[2] = {0.f, 0.f};

  auto load_tile = [&](int kt) -> StageRegs {
    StageRegs r;
    const _Float16* ks = kptr + (size_t)kt * 32 * U_;
    const _Float16* vs = vptr + (size_t)kt * 32;
    r.k0 = *(const half8*)ks;  r.k1 = *(const half8*)(ks + 8);
    r.v0 = *(const half8*)vs;  r.v1 = *(const half8*)(vs + 8);
    r.m  = (tid < 32) ? mptr[(size_t)kt * N_] : 0u;
    return r;
  };
  auto store_tile = [&](const StageRegs& r) {
    _Float16* kd = &Ks[(tid >> 4) * 264 + (tid & 15) * 16];
    *(half8*)kd = r.k0;  *(half8*)(kd + 8) = r.k1;
    _Float16* vd = &VTs[(tid >> 1) * 36 + (tid & 1) * 16];
    *(half8*)vd = r.v0;  *(half8*)(vd + 8) = r.v1;
    if (tid < 32) maskS[tid] = r.m;
  };
  auto compute_tile = [&]() {
    half8 ka0 = *(const half8*)&Ks[(0 * 16 + c) * 264 + w * D_ + qd * 8];
    half8 ka1 = *(const half8*)&Ks[(1 * 16 + c) * 264 + w * D_ + qd * 8];
    half4 va[2][2];
#pragma unroll
    for (int mt = 0; mt < 2; ++mt)
#pragma unroll
      for (int kc = 0; kc < 2; ++kc)
        va[mt][kc] = *(const half4*)&VTs[(w * D_ + mt * 16 + c) * 36 + kc * 16 + qd * 4];
#pragma unroll
    for (int nt = 0; nt < 2; ++nt) {
      float4v s0 = __builtin_amdgcn_mfma_f32_16x16x32_f16(ka0, qb[nt], init4, 0, 0, 0);
      float4v s1 = __builtin_amdgcn_mfma_f32_16x16x32_f16(ka1, qb[nt], init4, 0, 0, 0);
      const unsigned int mq = maskS[nt * 16 + c];
      const unsigned int t0 = mq >> (qd * 4);
      const unsigned int t1 = mq >> (16 + qd * 4);
      half4 pb0, pb1;
      float ls = 0.f;
#pragma unroll
      for (int r = 0; r < 4; ++r) {
        float e0 = fast_exp2(s0[r]);
        float e1 = fast_exp2(s1[r]);
        float p0 = ((t0 >> r) & 1u) ? e0 : 0.f;
        float p1 = ((t1 >> r) & 1u) ? e1 : 0.f;
        ls += p0 + p1;
        pb0[r] = (_Float16)p0;
        pb1[r] = (_Float16)p1;
      }
      lrow[nt] += ls;
      acc[0][nt] = __builtin_amdgcn_mfma_f32_16x16x16f16(va[0][0], pb0, acc[0][nt], 0, 0, 0);
      acc[0][nt] = __builtin_amdgcn_mfma_f32_16x16x16f16(va[0][1], pb1, acc[0][nt], 0, 0, 0);
      acc[1][nt] = __builtin_amdgcn_mfma_f32_16x16x16f16(va[1][0], pb0, acc[1][nt], 0, 0, 0);
      acc[1][nt] = __builtin_amdgcn_mfma_f32_16x16x16f16(va[1][1], pb1, acc[1][nt], 0, 0, 0);
    }
  };

  { // prologue
    StageRegs r = load_tile(0);
    store_tile(r);
  }
  __syncthreads();

#pragma unroll 1
  for (int kt = 0; kt < 64; ++kt) {
    const bool have = (kt + 1 < 64);
    StageRegs nxt;
    if (have) nxt = load_tile(kt + 1);   // in flight during compute(kt)
    compute_tile();
    __syncthreads();                     // all LDS reads of tile kt done
    if (have) store_tile(nxt);
    __syncthreads();                     // tile kt+1 visible
  }

  // epilogue: reduce l across qd-groups, normalize, transpose via LDS
  float rinv[2];
#pragma unroll
  for (int nt = 0; nt < 2; ++nt) {
    float l = lrow[nt];
    l += __shfl_xor(l, 16, 64);
    l += __shfl_xor(l, 32, 64);
    rinv[nt] = (l > 0.f) ? 1.f / l : 0.f;
  }
  _Float16* ctxS = (_Float16*)smem;  // [8 head][32 q][36]
#pragma unroll
  for (int mt = 0; mt < 2; ++mt)
#pragma unroll
    for (int nt = 0; nt < 2; ++nt) {
      half4 hv;
#pragma unroll
      for (int r = 0; r < 4; ++r)
        hv[r] = (_Float16)(acc[mt][nt][r] * rinv[nt]);
      *(half4*)&ctxS[w * 1152 + (nt * 16 + c) * 36 + mt * 16 + qd * 4] = hv;
    }
  __syncthreads();
  { // coalesced store: row = q, 16 threads cover the 256-feature row
    const int row = tid >> 4;        // 0..31
    const int rem = tid & 15;
    const int h2  = rem >> 1;        // head
    const int seg = rem & 1;         // 16-half segment
    _Float16* dst = Cg + (size_t)(b * N_ + q0 + row) * U_ + h2 * 32 + seg * 16;
    const _Float16* src = &ctxS[h2 * 1152 + row * 36 + seg * 16];
    *(half8*)dst       = *(const half8*)src;
    *(half8*)(dst + 8) = *(const half8*)(src + 8);
  }
}

// ---------------------------------------------------------------------------
// K3: output projection, LDS-free register GEMM, operand-swapped -> float4
// stores with float4 bias. grid (2,256): 64 rows x 128 cols per block.
// ---------------------------------------------------------------------------
__global__ __launch_bounds__(256, 4)
void k_out(const _Float16* __restrict__ Cg, const _Float16* __restrict__ WTo,
           const float* __restrict__ bo, float* __restrict__ Out)
{
  const int tid  = threadIdx.x;
  const int lane = tid & 63;
  const int w    = tid >> 6;
  const int c    = lane & 15;
  const int qd   = lane >> 4;
  const int n0l  = blockIdx.x * 128;
  const int m0   = blockIdx.y * 64;

  const _Float16* arow = Cg + (size_t)(m0 + w * 16 + c) * U_ + qd * 8;
  const _Float16* brow = WTo + (size_t)(n0l + c) * U_ + qd * 8;

  const float4v zero4 = {0.f, 0.f, 0.f, 0.f};
  float4v acc[8];
#pragma unroll
  for (int i = 0; i < 8; ++i) acc[i] = zero4;

#pragma unroll 2
  for (int ks = 0; ks < 8; ++ks) {
    const int k0 = ks * 32;
    half8 af = *(const half8*)(arow + k0);
    half8 bf[8];
#pragma unroll
    for (int nt = 0; nt < 8; ++nt)
      bf[nt] = *(const half8*)(brow + (size_t)nt * 16 * U_ + k0);
#pragma unroll
    for (int nt = 0; nt < 8; ++nt)
      acc[nt] = __builtin_amdgcn_mfma_f32_16x16x32_f16(bf[nt], af, acc[nt], 0, 0, 0);
  }

#pragma unroll
  for (int nt = 0; nt < 8; ++nt) {
    const float4v bias = *(const float4v*)(bo + n0l + nt * 16 + qd * 4);
    const int seq = m0 + w * 16 + c;
    float4v v = acc[nt] + bias;
    *(float4v*)(Out + (size_t)seq * U_ + n0l + nt * 16 + qd * 4) = v;
  }
}

// ---------------------------------------------------------------------------
extern "C" void kernel_launch(void* const* d_in, const int* in_sizes, int n_in,
                              void* d_out, int out_size, void* d_ws, size_t ws_size,
                              hipStream_t stream) {
  const float* X   = (const float*)d_in[0];
  const int*   Adj = (const int*)d_in[1];
  const float* Wq  = (const float*)d_in[2];
  const float* Wk  = (const float*)d_in[3];
  const float* Wv  = (const float*)d_in[4];
  const float* Wo  = (const float*)d_in[5];
  const float* bo  = (const float*)d_in[6];
  float* Out = (float*)d_out;

  const size_t elems = (size_t)B_ * N_ * U_;  // 4.19M halves = 8.39 MB each
  _Float16* Qg  = (_Float16*)d_ws;
  _Float16* Kg  = Qg + elems;
  _Float16* VTg = Kg + elems;
  _Float16* Xh  = VTg + elems;                // aliased: Cg reuses Xh after qkv
  _Float16* Cg  = Xh;
  _Float16* WT  = Xh + elems;                 // 4*256*256 halves = 512 KB
  unsigned int* mask32 = (unsigned int*)(WT + 4 * U_ * U_); // 4 MB

  k_prep<<<dim3(2576), 256, 0, stream>>>(X, Wq, Wk, Wv, Wo, Adj, Xh, WT, mask32);
  k_qkv<<<dim3(6, 256), 256, 0, stream>>>(Xh, WT, Qg, Kg, VTg);
  k_attn<<<dim3(512), 512, 0, stream>>>(Qg, Kg, VTg, mask32, Cg);
  k_out<<<dim3(2, 256), 256, 0, stream>>>(Cg, WT + 3 * U_ * U_, bo, Out);
}

// Round 8
// 394.629 us; speedup vs baseline: 2.6407x; 1.0827x over previous
//
#include <hip/hip_runtime.h>
#include <cstdint>
#include <cstddef>

#define B_ 8
#define N_ 2048
#define H_ 8
#define D_ 32
#define U_ 256

typedef _Float16 half8 __attribute__((ext_vector_type(8)));
typedef _Float16 half4 __attribute__((ext_vector_type(4)));
typedef float float4v __attribute__((ext_vector_type(4)));

__device__ __forceinline__ float fast_exp2(float x) {
#if __has_builtin(__builtin_amdgcn_exp2f)
  return __builtin_amdgcn_exp2f(x);
#else
  return exp2f(x);
#endif
}

// ---------------------------------------------------------------------------
// K0: prep (528 blocks).
//  bid 0..15  : transpose W{q,k,v,o} -> WT[m][n][k] fp16; q-scale folded.
//  bid 16..527: X fp32 -> fp16 (Xh).
// ---------------------------------------------------------------------------
__global__ __launch_bounds__(256)
void k_prep(const float* __restrict__ X,
            const float* __restrict__ Wq, const float* __restrict__ Wk,
            const float* __restrict__ Wv, const float* __restrict__ Wo,
            _Float16* __restrict__ Xh, _Float16* __restrict__ WT)
{
  const int bid = blockIdx.x, tid = threadIdx.x;
  if (bid < 16) {
    const int m = bid >> 2;            // 0=q 1=k 2=v 3=o
    const int n0 = (bid & 3) * 64;     // 64-col slice
    const float* W = (m == 0) ? Wq : (m == 1) ? Wk : (m == 2) ? Wv : Wo;
    const float scale = (m == 0) ? 0.25505413f : 1.0f; // log2(e)/sqrt(32)
    _Float16* T = WT + (size_t)m * U_ * U_;
    __shared__ _Float16 Ts[64][72];
    const int r = tid >> 2, seg = tid & 3;
    for (int t = 0; t < 4; ++t) {
      const int k0 = t * 64;
      float4v a[4];
      const float* s = W + (size_t)(k0 + r) * U_ + n0 + seg * 16;
#pragma unroll
      for (int i = 0; i < 4; ++i) a[i] = *(const float4v*)(s + i * 4);
      __syncthreads();
#pragma unroll
      for (int i = 0; i < 4; ++i)
#pragma unroll
        for (int j = 0; j < 4; ++j)
          Ts[seg * 16 + i * 4 + j][r] = (_Float16)(a[i][j] * scale);
      __syncthreads();
      _Float16* d = T + (size_t)(n0 + r) * U_ + k0 + seg * 16;
      *(half8*)d       = *(const half8*)&Ts[r][seg * 16];
      *(half8*)(d + 8) = *(const half8*)&Ts[r][seg * 16 + 8];
    }
  } else {
    const size_t base = ((size_t)(bid - 16) * 256 + tid) * 32;
    const float* src = X + base;
    _Float16* dst = Xh + base;
#pragma unroll
    for (int i = 0; i < 4; ++i) {
      float4v a = *(const float4v*)(src + i * 8);
      float4v b = *(const float4v*)(src + i * 8 + 4);
      half8 h;
      h[0] = (_Float16)a[0]; h[1] = (_Float16)a[1];
      h[2] = (_Float16)a[2]; h[3] = (_Float16)a[3];
      h[4] = (_Float16)b[0]; h[5] = (_Float16)b[1];
      h[6] = (_Float16)b[2]; h[7] = (_Float16)b[3];
      *(half8*)(dst + i * 8) = h;
    }
  }
}

// ---------------------------------------------------------------------------
// K1: QKV projection, LDS-free register GEMM on fp16 Xh. grid (6,256):
// proj = bx>>1, 128-col half = bx&1; 64 rows/block (wave = 16 rows), K=256.
// Q/K: operand-swapped mfma -> half4 feature-stores. V: normal order ->
// half4 seq-stores into VT[b][u][n].
// ---------------------------------------------------------------------------
__global__ __launch_bounds__(256, 4)
void k_qkv(const _Float16* __restrict__ Xh, const _Float16* __restrict__ WT,
           _Float16* __restrict__ Qg, _Float16* __restrict__ Kg,
           _Float16* __restrict__ VTg)
{
  const int tid  = threadIdx.x;
  const int lane = tid & 63;
  const int w    = tid >> 6;
  const int c    = lane & 15;
  const int qd   = lane >> 4;
  const int bx   = blockIdx.x;
  const int proj = bx >> 1;
  const int n0l  = (bx & 1) * 128;
  const int m0   = blockIdx.y * 64;

  const _Float16* Wp = WT + (size_t)proj * U_ * U_;
  const _Float16* arow = Xh + (size_t)(m0 + w * 16 + c) * U_ + qd * 8;
  const _Float16* brow = Wp + (size_t)(n0l + c) * U_ + qd * 8;

  const float4v zero4 = {0.f, 0.f, 0.f, 0.f};
  float4v acc[8];
#pragma unroll
  for (int i = 0; i < 8; ++i) acc[i] = zero4;

#pragma unroll 2
  for (int ks = 0; ks < 8; ++ks) {
    const int k0 = ks * 32;
    half8 af = *(const half8*)(arow + k0);
    half8 bf[8];
#pragma unroll
    for (int nt = 0; nt < 8; ++nt)
      bf[nt] = *(const half8*)(brow + (size_t)nt * 16 * U_ + k0);
    if (proj < 2) {
#pragma unroll
      for (int nt = 0; nt < 8; ++nt)
        acc[nt] = __builtin_amdgcn_mfma_f32_16x16x32_f16(bf[nt], af, acc[nt], 0, 0, 0);
    } else {
#pragma unroll
      for (int nt = 0; nt < 8; ++nt)
        acc[nt] = __builtin_amdgcn_mfma_f32_16x16x32_f16(af, bf[nt], acc[nt], 0, 0, 0);
    }
  }

  const int b   = m0 >> 11;
  const int nb0 = m0 & (N_ - 1);
  if (proj < 2) {
    _Float16* Og = (proj == 0) ? Qg : Kg;
#pragma unroll
    for (int nt = 0; nt < 8; ++nt) {
      half4 hv;
#pragma unroll
      for (int r = 0; r < 4; ++r) hv[r] = (_Float16)acc[nt][r];
      const int seq = nb0 + w * 16 + c;
      *(half4*)(Og + (size_t)(b * N_ + seq) * U_ + n0l + nt * 16 + qd * 4) = hv;
    }
  } else {
#pragma unroll
    for (int nt = 0; nt < 8; ++nt) {
      half4 hv;
#pragma unroll
      for (int r = 0; r < 4; ++r) hv[r] = (_Float16)acc[nt][r];
      const int u = n0l + nt * 16 + c;
      const int seq = nb0 + w * 16 + qd * 4;
      *(half4*)(VTg + (size_t)(b * U_ + u) * N_ + seq) = hv;
    }
  }
}

// ---------------------------------------------------------------------------
// K2: FULLY-FUSED masked flash attention + output projection.
// Tq=32, Tk=32, grid 512, block 512 = 8 waves = 8 heads. Single-buffered LDS
// (34.6 KB, 4 blocks/CU). Barrier-anchored register prefetch of tile kt+1.
// Adjacency ballots inline (Adj streamed once, overlapped with compute).
// Fixed-bias softmax p = exp2(s-8) (bias cancels in p/l). S^T = K*Q^T; P^T
// exits QK in B-layout of mfma 16x16x16f16 -> PV in registers.
// Epilogue: ctx[32 q][256 u] parked in LDS (reusing Ks), in-block GEMM vs
// WTo (L2-hot) with operand-swap -> float4 stores of fp32 Out + bias.
// ---------------------------------------------------------------------------
#define KS_B 16896   // 32*264*2
#define VT_B 18432   // 256*36*2

struct StageRegs {
  half8 k0, k1, v0, v1;
  int a0, a1;
};

__global__ __launch_bounds__(512, 4)
void k_attn(const _Float16* __restrict__ Qg, const _Float16* __restrict__ Kg,
            const _Float16* __restrict__ VTg, const int* __restrict__ Adj,
            const _Float16* __restrict__ WTo, const float* __restrict__ bo,
            float* __restrict__ Out)
{
  __shared__ __attribute__((aligned(16))) char smem[KS_B + VT_B + 128];
  _Float16* Ks  = (_Float16*)smem;              // [32 key][264]
  _Float16* VTs = (_Float16*)(smem + KS_B);     // [256 u][36]
  unsigned int* maskS = (unsigned int*)(smem + KS_B + VT_B); // [32 q]

  const int tid  = threadIdx.x;
  const int lane = tid & 63;
  const int w    = tid >> 6;   // head
  const int c    = lane & 15;
  const int qd   = lane >> 4;
  const int wg   = blockIdx.x;
  const int b    = wg & 7;     // batch <-> XCD affinity
  const int q0   = (wg >> 3) * 32;

  const _Float16* kptr = Kg + (size_t)(b * N_ + (tid >> 4)) * U_ + (tid & 15) * 16;
  const _Float16* vptr = VTg + (size_t)(b * U_ + (tid >> 1)) * N_ + (tid & 1) * 16;
  const int rr = lane >> 5;
  const int kk = lane & 31;
  const int* aptr = Adj + (size_t)(b * N_ + q0 + w * 4 + rr) * N_ + kk;

  half8 qb[2];
#pragma unroll
  for (int nt = 0; nt < 2; ++nt)
    qb[nt] = *(const half8*)(Qg + (size_t)(b * N_ + q0 + nt * 16 + c) * U_ + w * D_ + qd * 8);

  const float4v init4 = {-8.f, -8.f, -8.f, -8.f}; // exp2 bias, cancels in p/l
  const float4v zero4 = {0.f, 0.f, 0.f, 0.f};
  float4v acc[2][2];
#pragma unroll
  for (int i = 0; i < 2; ++i)
#pragma unroll
    for (int j = 0; j < 2; ++j) acc[i][j] = zero4;
  float lrow[2] = {0.f, 0.f};

  auto load_tile = [&](int kt) -> StageRegs {
    StageRegs r;
    const _Float16* ks = kptr + (size_t)kt * 32 * U_;
    const _Float16* vs = vptr + (size_t)kt * 32;
    const int* as = aptr + (size_t)kt * 32;
    r.k0 = *(const half8*)ks;  r.k1 = *(const half8*)(ks + 8);
    r.v0 = *(const half8*)vs;  r.v1 = *(const half8*)(vs + 8);
    r.a0 = as[0];                 // rows w*4 + rr
    r.a1 = as[2 * (size_t)N_];    // rows w*4 + 2 + rr
    return r;
  };
  auto store_tile = [&](const StageRegs& r) {
    _Float16* kd = &Ks[(tid >> 4) * 264 + (tid & 15) * 16];
    *(half8*)kd = r.k0;  *(half8*)(kd + 8) = r.k1;
    _Float16* vd = &VTs[(tid >> 1) * 36 + (tid & 1) * 16];
    *(half8*)vd = r.v0;  *(half8*)(vd + 8) = r.v1;
    unsigned long long bm;
    bm = __ballot(r.a0 > 0); if (lane == 0) *(unsigned long long*)&maskS[w * 4 + 0] = bm;
    bm = __ballot(r.a1 > 0); if (lane == 0) *(unsigned long long*)&maskS[w * 4 + 2] = bm;
  };
  auto compute_tile = [&]() {
    half8 ka0 = *(const half8*)&Ks[(0 * 16 + c) * 264 + w * D_ + qd * 8];
    half8 ka1 = *(const half8*)&Ks[(1 * 16 + c) * 264 + w * D_ + qd * 8];
    half4 va[2][2];
#pragma unroll
    for (int mt = 0; mt < 2; ++mt)
#pragma unroll
      for (int kc = 0; kc < 2; ++kc)
        va[mt][kc] = *(const half4*)&VTs[(w * D_ + mt * 16 + c) * 36 + kc * 16 + qd * 4];
#pragma unroll
    for (int nt = 0; nt < 2; ++nt) {
      float4v s0 = __builtin_amdgcn_mfma_f32_16x16x32_f16(ka0, qb[nt], init4, 0, 0, 0);
      float4v s1 = __builtin_amdgcn_mfma_f32_16x16x32_f16(ka1, qb[nt], init4, 0, 0, 0);
      const unsigned int mq = maskS[nt * 16 + c];
      const unsigned int t0 = mq >> (qd * 4);
      const unsigned int t1 = mq >> (16 + qd * 4);
      half4 pb0, pb1;
      float ls = 0.f;
#pragma unroll
      for (int r = 0; r < 4; ++r) {
        float e0 = fast_exp2(s0[r]);
        float e1 = fast_exp2(s1[r]);
        float p0 = ((t0 >> r) & 1u) ? e0 : 0.f;
        float p1 = ((t1 >> r) & 1u) ? e1 : 0.f;
        ls += p0 + p1;
        pb0[r] = (_Float16)p0;
        pb1[r] = (_Float16)p1;
      }
      lrow[nt] += ls;
      acc[0][nt] = __builtin_amdgcn_mfma_f32_16x16x16f16(va[0][0], pb0, acc[0][nt], 0, 0, 0);
      acc[0][nt] = __builtin_amdgcn_mfma_f32_16x16x16f16(va[0][1], pb1, acc[0][nt], 0, 0, 0);
      acc[1][nt] = __builtin_amdgcn_mfma_f32_16x16x16f16(va[1][0], pb0, acc[1][nt], 0, 0, 0);
      acc[1][nt] = __builtin_amdgcn_mfma_f32_16x16x16f16(va[1][1], pb1, acc[1][nt], 0, 0, 0);
    }
  };

  { // prologue
    StageRegs r = load_tile(0);
    store_tile(r);
  }
  __syncthreads();

#pragma unroll 1
  for (int kt = 0; kt < 64; ++kt) {
    const bool have = (kt + 1 < 64);
    StageRegs nxt;
    if (have) nxt = load_tile(kt + 1);   // in flight during compute(kt)
    compute_tile();
    __syncthreads();                     // all LDS reads of tile kt done
    if (have) store_tile(nxt);
    __syncthreads();                     // tile kt+1 visible
  }

  // ---- epilogue 1: normalize, park ctx[32 q][256 u] in LDS (reuse Ks) ----
  float rinv[2];
#pragma unroll
  for (int nt = 0; nt < 2; ++nt) {
    float l = lrow[nt];
    l += __shfl_xor(l, 16, 64);
    l += __shfl_xor(l, 32, 64);
    rinv[nt] = (l > 0.f) ? 1.f / l : 0.f;
  }
  _Float16* ctxS = (_Float16*)smem;  // [32 q][264]
#pragma unroll
  for (int mt = 0; mt < 2; ++mt)
#pragma unroll
    for (int nt = 0; nt < 2; ++nt) {
      half4 hv;
#pragma unroll
      for (int r = 0; r < 4; ++r)
        hv[r] = (_Float16)(acc[mt][nt][r] * rinv[nt]);
      // q row = nt*16 + c ; features u = w*32 + mt*16 + qd*4 ..+3
      *(half4*)&ctxS[(nt * 16 + c) * 264 + w * D_ + mt * 16 + qd * 4] = hv;
    }
  __syncthreads();

  // ---- epilogue 2: fused output projection Out[q][n] = ctx @ Wo + bo ----
  // wave w owns output features n = w*32 .. w*32+31 (M-dim, 2 tiles of 16);
  // N-dim = 32 q rows (2 tiles). A = WTo rows (global, L2-hot), B = ctx (LDS).
  float4v oacc[2][2];
#pragma unroll
  for (int i = 0; i < 2; ++i)
#pragma unroll
    for (int j = 0; j < 2; ++j) oacc[i][j] = zero4;

  const _Float16* wrow = WTo + (size_t)(w * 32 + c) * U_ + qd * 8;
#pragma unroll 2
  for (int ks = 0; ks < 8; ++ks) {
    const int k0 = ks * 32;
    half8 aw0 = *(const half8*)(wrow + k0);
    half8 aw1 = *(const half8*)(wrow + (size_t)16 * U_ + k0);
    half8 bq0 = *(const half8*)&ctxS[(0 * 16 + c) * 264 + k0 + qd * 8];
    half8 bq1 = *(const half8*)&ctxS[(1 * 16 + c) * 264 + k0 + qd * 8];
    oacc[0][0] = __builtin_amdgcn_mfma_f32_16x16x32_f16(aw0, bq0, oacc[0][0], 0, 0, 0);
    oacc[0][1] = __builtin_amdgcn_mfma_f32_16x16x32_f16(aw0, bq1, oacc[0][1], 0, 0, 0);
    oacc[1][0] = __builtin_amdgcn_mfma_f32_16x16x32_f16(aw1, bq0, oacc[1][0], 0, 0, 0);
    oacc[1][1] = __builtin_amdgcn_mfma_f32_16x16x32_f16(aw1, bq1, oacc[1][1], 0, 0, 0);
  }

#pragma unroll
  for (int mt = 0; mt < 2; ++mt) {
    const float4v bias = *(const float4v*)(bo + w * 32 + mt * 16 + qd * 4);
#pragma unroll
    for (int nt = 0; nt < 2; ++nt) {
      const int q = q0 + nt * 16 + c;
      float4v v = oacc[mt][nt] + bias;
      *(float4v*)(Out + (size_t)(b * N_ + q) * U_ + w * 32 + mt * 16 + qd * 4) = v;
    }
  }
}

// ---------------------------------------------------------------------------
extern "C" void kernel_launch(void* const* d_in, const int* in_sizes, int n_in,
                              void* d_out, int out_size, void* d_ws, size_t ws_size,
                              hipStream_t stream) {
  const float* X   = (const float*)d_in[0];
  const int*   Adj = (const int*)d_in[1];
  const float* Wq  = (const float*)d_in[2];
  const float* Wk  = (const float*)d_in[3];
  const float* Wv  = (const float*)d_in[4];
  const float* Wo  = (const float*)d_in[5];
  const float* bo  = (const float*)d_in[6];
  float* Out = (float*)d_out;

  const size_t elems = (size_t)B_ * N_ * U_;  // 4.19M halves = 8.39 MB each
  _Float16* Qg  = (_Float16*)d_ws;
  _Float16* Kg  = Qg + elems;
  _Float16* VTg = Kg + elems;
  _Float16* Xh  = VTg + elems;
  _Float16* WT  = Xh + elems;                 // 4*256*256 halves = 512 KB

  k_prep<<<dim3(528), 256, 0, stream>>>(X, Wq, Wk, Wv, Wo, Xh, WT);
  k_qkv<<<dim3(6, 256), 256, 0, stream>>>(Xh, WT, Qg, Kg, VTg);
  k_attn<<<dim3(512), 512, 0, stream>>>(Qg, Kg, VTg, Adj, WT + 3 * U_ * U_, bo, Out);
}